// Round 1
// baseline (2863.566 us; speedup 1.0000x reference)
//
#include <hip/hip_runtime.h>
#include <math.h>

#define BGR 256        // graphs
#define NPG0 400       // nodes per graph (initial)
#define NN (BGR*NPG0)  // 102400 nodes
#define NE (NN*16)     // 1638400 edges
#define HD 128
#define CAP 64         // max in-degree capacity

// ---------------- CSR build (fixed capacity, by dst) ----------------
__global__ void k_build(const int* __restrict__ src, const int* __restrict__ dst,
                        int* __restrict__ cnt, int* __restrict__ col) {
    int e = blockIdx.x * 256 + threadIdx.x;
    if (e >= NE) return;
    int d = dst[e];
    int s = src[e];
    int i = atomicAdd(&cnt[d], 1);
    if (i < CAP) col[d * CAP + i] = s;
}

__global__ void k_init_alive(float* __restrict__ alive) {
    int i = blockIdx.x * 256 + threadIdx.x;
    if (i < NN) alive[i] = 1.0f;
}

// ---------------- mean aggregation: mean[o][f] = sum_{e in(o), alive src} x[src][f] / max(#alive,1)
// block (128,2): 2 nodes per block, feature-parallel
__global__ __launch_bounds__(256) void k_agg(const float* __restrict__ x,
                      const int* __restrict__ cnt, const int* __restrict__ col,
                      const float* __restrict__ alive, float* __restrict__ mean) {
    int o = blockIdx.x * 2 + threadIdx.y;
    int f = threadIdx.x;
    if (alive[o] == 0.0f) return;
    int n = cnt[o]; if (n > CAP) n = CAP;
    const int* c = &col[o * CAP];
    float acc = 0.0f, live = 0.0f;
    for (int i = 0; i < n; i++) {
        int s = c[i];
        acc  += x[(long)s * HD + f];   // dead rows are zeroed -> contribute 0
        live += alive[s];
    }
    mean[(long)o * HD + f] = acc / fmaxf(live, 1.0f);
}

// ---------------- conv GEMM: xout[o] = relu(mean[o]@Wr + xin[o]@Ws + b), 16 nodes/block
__global__ __launch_bounds__(256) void k_conv(const float* __restrict__ xin, float* __restrict__ xout,
    const float* __restrict__ mean, const float* __restrict__ alive,
    const float* __restrict__ Wr, const float* __restrict__ Ws, const float* __restrict__ bias) {
    __shared__ __align__(16) float sm[16][HD];
    __shared__ __align__(16) float sx[16][HD];
    int t = threadIdx.x;
    long base = (long)blockIdx.x * 16;
    for (int idx = t; idx < 16 * HD; idx += 256) {
        int n = idx >> 7, f = idx & 127;
        long o = base + n;
        sm[n][f] = mean[o * HD + f];   // dead rows: garbage but finite; skipped at write
        sx[n][f] = xin[o * HD + f];
    }
    __syncthreads();
    int j = t & 127, grp = t >> 7;
    float b = bias[j];
    float acc[8];
#pragma unroll
    for (int ni = 0; ni < 8; ni++) acc[ni] = b;

    const float4* smv = (const float4*)&sm[grp * 8][0];
    for (int k4 = 0; k4 < 32; k4++) {
        float w0 = Wr[(k4 * 4 + 0) * HD + j];
        float w1 = Wr[(k4 * 4 + 1) * HD + j];
        float w2 = Wr[(k4 * 4 + 2) * HD + j];
        float w3 = Wr[(k4 * 4 + 3) * HD + j];
#pragma unroll
        for (int ni = 0; ni < 8; ni++) {
            float4 m = smv[ni * 32 + k4];
            acc[ni] += m.x * w0 + m.y * w1 + m.z * w2 + m.w * w3;
        }
    }
    const float4* sxv = (const float4*)&sx[grp * 8][0];
    for (int k4 = 0; k4 < 32; k4++) {
        float w0 = Ws[(k4 * 4 + 0) * HD + j];
        float w1 = Ws[(k4 * 4 + 1) * HD + j];
        float w2 = Ws[(k4 * 4 + 2) * HD + j];
        float w3 = Ws[(k4 * 4 + 3) * HD + j];
#pragma unroll
        for (int ni = 0; ni < 8; ni++) {
            float4 m = sxv[ni * 32 + k4];
            acc[ni] += m.x * w0 + m.y * w1 + m.z * w2 + m.w * w3;
        }
    }
#pragma unroll
    for (int ni = 0; ni < 8; ni++) {
        long o = base + grp * 8 + ni;
        if (alive[o] != 0.0f) xout[o * HD + j] = fmaxf(acc[ni], 0.0f);
    }
}

// ---------------- per-graph feature sum / npg  ->  h[g][layer*128 + f]
__global__ void k_gsum(const float* __restrict__ x, float* __restrict__ h,
                       int layer, float npg) {
    int g = blockIdx.x, f = threadIdx.x;
    const float* p = &x[(long)g * NPG0 * HD + f];
    float acc = 0.0f;
    for (int i = 0; i < NPG0; i++) acc += p[(long)i * HD];  // dead rows are 0
    h[g * (5 * HD) + layer * HD + f] = acc / npg;
}

// ---------------- SAG score: score[o] = mean[o].wr + x[o].ws + b  (dead -> -inf)
// block (64,4): one wave per node
__global__ __launch_bounds__(256) void k_score(const float* __restrict__ x, const float* __restrict__ mean,
    const float* __restrict__ alive, const float* __restrict__ wr,
    const float* __restrict__ ws, const float* __restrict__ pb,
    float* __restrict__ score) {
    int o = blockIdx.x * 4 + threadIdx.y;
    int l = threadIdx.x;
    if (alive[o] == 0.0f) {
        if (l == 0) score[o] = -INFINITY;
        return;
    }
    long ob = (long)o * HD;
    float v = mean[ob + l] * wr[l] + mean[ob + l + 64] * wr[l + 64]
            + x[ob + l] * ws[l] + x[ob + l + 64] * ws[l + 64];
    for (int off = 32; off; off >>= 1) v += __shfl_down(v, off);
    if (l == 0) score[o] = v + pb[0];
}

// ---------------- per-graph top-K: keep K best (ties: lowest index), scale kept x by tanh(score), zero dropped
__global__ __launch_bounds__(256) void k_topk(float* __restrict__ x, float* __restrict__ alive,
                        const float* __restrict__ score, int K) {
    __shared__ float s[512];
    __shared__ float sc[NPG0];
    __shared__ float mult[NPG0];
    __shared__ unsigned char keep[NPG0];
    __shared__ int cnt_gt;
    int g = blockIdx.x, t = threadIdx.x;
    long nb = (long)g * NPG0;
    for (int i = t; i < 512; i += 256) {
        float v = (i < NPG0) ? score[nb + i] : -INFINITY;
        s[i] = v;
        if (i < NPG0) sc[i] = v;
    }
    if (t == 0) cnt_gt = 0;
    __syncthreads();
    // bitonic sort ascending (512 elements, 256 threads)
    for (int ksz = 2; ksz <= 512; ksz <<= 1) {
        for (int jsz = ksz >> 1; jsz >= 1; jsz >>= 1) {
            for (int i = t; i < 512; i += 256) {
                int ixj = i ^ jsz;
                if (ixj > i) {
                    float a = s[i], c = s[ixj];
                    bool up = ((i & ksz) == 0);
                    if ((a > c) == up) { s[i] = c; s[ixj] = a; }
                }
            }
            __syncthreads();
        }
    }
    float thr = s[512 - K];
    for (int n = t; n < NPG0; n += 256)
        if (sc[n] > thr) atomicAdd(&cnt_gt, 1);
    __syncthreads();
    if (t == 0) {
        int m = K - cnt_gt, tk = 0;
        for (int n = 0; n < NPG0; n++) {
            bool kp = sc[n] > thr;
            if (!kp && sc[n] == thr && tk < m) { kp = true; tk++; }
            keep[n] = kp ? 1 : 0;
        }
    }
    __syncthreads();
    for (int n = t; n < NPG0; n += 256) {
        mult[n] = keep[n] ? tanhf(sc[n]) : 0.0f;
        alive[nb + n] = keep[n] ? 1.0f : 0.0f;
    }
    __syncthreads();
    for (int idx = t; idx < NPG0 * HD; idx += 256) {
        int n = idx >> 7, f = idx & 127;
        x[(nb + n) * HD + f] *= mult[n];
    }
}

// ---------------- final MLP + log_softmax, one block per graph
__global__ __launch_bounds__(128) void k_mlp(const float* __restrict__ h, const float* __restrict__ w1,
    const float* __restrict__ b1, const float* __restrict__ w2,
    const float* __restrict__ b2, float* __restrict__ out) {
    __shared__ float h1[HD];
    __shared__ float red[HD];
    __shared__ float lg[2];
    int g = blockIdx.x, j = threadIdx.x;
    const float* hg = &h[g * (5 * HD)];
    float acc = b1[j];
    for (int k = 0; k < 5 * HD; k++) acc += hg[k] * w1[k * HD + j];
    h1[j] = fmaxf(acc, 0.0f);
    __syncthreads();
    for (int c = 0; c < 2; c++) {
        red[j] = h1[j] * w2[j * 2 + c];
        __syncthreads();
        for (int st = 64; st > 0; st >>= 1) {
            if (j < st) red[j] += red[j + st];
            __syncthreads();
        }
        if (j == 0) lg[c] = red[0] + b2[c];
        __syncthreads();
    }
    if (j == 0) {
        float l0 = lg[0], l1 = lg[1];
        float m = fmaxf(l0, l1);
        float lse = m + logf(expf(l0 - m) + expf(l1 - m));
        out[g * 2 + 0] = l0 - lse;
        out[g * 2 + 1] = l1 - lse;
    }
}

extern "C" void kernel_launch(void* const* d_in, const int* in_sizes, int n_in,
                              void* d_out, int out_size, void* d_ws, size_t ws_size,
                              hipStream_t stream) {
    const float* x_in   = (const float*)d_in[0];
    const int*   eidx   = (const int*)d_in[1];
    const int*   e_src  = eidx;
    const int*   e_dst  = eidx + NE;
    const float* c1_wr  = (const float*)d_in[3];
    const float* c1_ws  = (const float*)d_in[4];
    const float* c1_b   = (const float*)d_in[5];
    const float* cs_wr  = (const float*)d_in[6];
    const float* cs_ws  = (const float*)d_in[7];
    const float* cs_b   = (const float*)d_in[8];
    const float* p_wr   = (const float*)d_in[9];
    const float* p_ws   = (const float*)d_in[10];
    const float* p_b    = (const float*)d_in[11];
    const float* l1_w   = (const float*)d_in[12];
    const float* l1_b   = (const float*)d_in[13];
    const float* l2_w   = (const float*)d_in[14];
    const float* l2_b   = (const float*)d_in[15];
    float* out = (float*)d_out;

    char* ws = (char*)d_ws;
    size_t off = 0;
    int*   cnt   = (int*)(ws + off);   off += (size_t)NN * 4;            // 409600
    int*   col   = (int*)(ws + off);   off += (size_t)NN * CAP * 4;      // 26214400
    float* alive = (float*)(ws + off); off += (size_t)NN * 4;
    float* xbuf  = (float*)(ws + off); off += (size_t)NN * HD * 4;       // 52428800
    float* meanb = (float*)(ws + off); off += (size_t)NN * HD * 4;
    float* score = (float*)(ws + off); off += (size_t)NN * 4;
    float* hcat  = (float*)(ws + off); off += (size_t)BGR * 5 * HD * 4;

    hipMemsetAsync(cnt, 0, (size_t)NN * 4, stream);
    k_build<<<(NE + 255) / 256, 256, 0, stream>>>(e_src, e_dst, cnt, col);
    k_init_alive<<<(NN + 255) / 256, 256, 0, stream>>>(alive);

    dim3 aggB(128, 2), scB(64, 4);

    // conv1 (reads x_in, writes xbuf)
    k_agg<<<NN / 2, aggB, 0, stream>>>(x_in, cnt, col, alive, meanb);
    k_conv<<<NN / 16, 256, 0, stream>>>(x_in, xbuf, meanb, alive, c1_wr, c1_ws, c1_b);
    k_gsum<<<BGR, HD, 0, stream>>>(xbuf, hcat, 0, 400.0f);

    // convs[0]
    k_agg<<<NN / 2, aggB, 0, stream>>>(xbuf, cnt, col, alive, meanb);
    k_conv<<<NN / 16, 256, 0, stream>>>(xbuf, xbuf, meanb, alive, cs_wr + 0 * HD * HD, cs_ws + 0 * HD * HD, cs_b + 0 * HD);
    k_gsum<<<BGR, HD, 0, stream>>>(xbuf, hcat, 1, 400.0f);

    // pool 0 (k = 320)
    k_agg<<<NN / 2, aggB, 0, stream>>>(xbuf, cnt, col, alive, meanb);
    k_score<<<NN / 4, scB, 0, stream>>>(xbuf, meanb, alive, p_wr + 0 * HD, p_ws + 0 * HD, p_b + 0, score);
    k_topk<<<BGR, 256, 0, stream>>>(xbuf, alive, score, 320);

    // convs[1]
    k_agg<<<NN / 2, aggB, 0, stream>>>(xbuf, cnt, col, alive, meanb);
    k_conv<<<NN / 16, 256, 0, stream>>>(xbuf, xbuf, meanb, alive, cs_wr + 1 * HD * HD, cs_ws + 1 * HD * HD, cs_b + 1 * HD);
    k_gsum<<<BGR, HD, 0, stream>>>(xbuf, hcat, 2, 320.0f);

    // convs[2]
    k_agg<<<NN / 2, aggB, 0, stream>>>(xbuf, cnt, col, alive, meanb);
    k_conv<<<NN / 16, 256, 0, stream>>>(xbuf, xbuf, meanb, alive, cs_wr + 2 * HD * HD, cs_ws + 2 * HD * HD, cs_b + 2 * HD);
    k_gsum<<<BGR, HD, 0, stream>>>(xbuf, hcat, 3, 320.0f);

    // pool 1 (k = 256)
    k_agg<<<NN / 2, aggB, 0, stream>>>(xbuf, cnt, col, alive, meanb);
    k_score<<<NN / 4, scB, 0, stream>>>(xbuf, meanb, alive, p_wr + 1 * HD, p_ws + 1 * HD, p_b + 1, score);
    k_topk<<<BGR, 256, 0, stream>>>(xbuf, alive, score, 256);

    // convs[3]
    k_agg<<<NN / 2, aggB, 0, stream>>>(xbuf, cnt, col, alive, meanb);
    k_conv<<<NN / 16, 256, 0, stream>>>(xbuf, xbuf, meanb, alive, cs_wr + 3 * HD * HD, cs_ws + 3 * HD * HD, cs_b + 3 * HD);
    k_gsum<<<BGR, HD, 0, stream>>>(xbuf, hcat, 4, 256.0f);

    // MLP head
    k_mlp<<<BGR, HD, 0, stream>>>(hcat, l1_w, l1_b, l2_w, l2_b, out);
}

// Round 2
// 1386.604 us; speedup vs baseline: 2.0652x; 2.0652x over previous
//
#include <hip/hip_runtime.h>
#include <math.h>

#define BGR 256        // graphs
#define NPG0 400       // nodes per graph (initial)
#define NN (BGR*NPG0)  // 102400 nodes
#define NE (NN*16)     // 1638400 edges
#define HD 128
#define CAP 64         // max in-degree capacity

__device__ __forceinline__ float4 f4add(float4 a, float4 b) {
    return make_float4(a.x + b.x, a.y + b.y, a.z + b.z, a.w + b.w);
}

// ---------------- CSR build (fixed capacity, by dst) ----------------
__global__ void k_build(const int* __restrict__ src, const int* __restrict__ dst,
                        int* __restrict__ cnt, int* __restrict__ col) {
    int e = blockIdx.x * 256 + threadIdx.x;
    if (e >= NE) return;
    int d = dst[e];
    int s = src[e];
    int i = atomicAdd(&cnt[d], 1);
    if (i < CAP) col[d * CAP + i] = s;
}

__global__ void k_init_alive(float* __restrict__ alive) {
    int i = blockIdx.x * 256 + threadIdx.x;
    if (i < NN) alive[i] = 1.0f;
}

// rliv[o] = 1 / max(sum_j alive[src_j], 1)  — recomputed only when topology changes
__global__ void k_rliv(const int* __restrict__ cnt, const int* __restrict__ col,
                       const float* __restrict__ alive, float* __restrict__ rliv) {
    int o = blockIdx.x * 256 + threadIdx.x;
    if (o >= NN) return;
    int n = cnt[o]; if (n > CAP) n = CAP;
    const int* c = &col[(long)o * CAP];
    float s = 0.0f;
    for (int i = 0; i < n; i++) s += alive[c[i]];
    rliv[o] = 1.0f / fmaxf(s, 1.0f);
}

// ---------------- mean aggregation, float4 + 4-way unroll + XCD swizzle
// block (32,8): 8 nodes/block, 32 lanes * float4 per node row
__global__ __launch_bounds__(256) void k_agg(const float* __restrict__ x,
                      const int* __restrict__ cnt, const int* __restrict__ col,
                      const float* __restrict__ alive, const float* __restrict__ rliv,
                      float* __restrict__ mean) {
    // XCD-aware swizzle: blockIdx%8 -> XCD (heuristic). All 50 blocks of a graph
    // land on one XCD so its 200KB x-slice stays L2-resident.
    int b = blockIdx.x;
    int r = b & 7, q = b >> 3;            // q in 0..1599
    int g = r + (q / 50) * 8;             // graph id
    int o = g * NPG0 + (q % 50) * 8 + threadIdx.y;
    if (alive[o] == 0.0f) return;
    int lane = threadIdx.x;
    int n = cnt[o]; if (n > CAP) n = CAP;
    const int* c = &col[(long)o * CAP];
    const float4* xv = (const float4*)x;
    float4 a0 = make_float4(0, 0, 0, 0), a1 = a0, a2 = a0, a3 = a0;
    int i = 0;
    for (; i + 4 <= n; i += 4) {
        int s0 = c[i], s1 = c[i + 1], s2 = c[i + 2], s3 = c[i + 3];
        float4 v0 = xv[s0 * 32 + lane];
        float4 v1 = xv[s1 * 32 + lane];
        float4 v2 = xv[s2 * 32 + lane];
        float4 v3 = xv[s3 * 32 + lane];
        a0 = f4add(a0, v0); a1 = f4add(a1, v1);
        a2 = f4add(a2, v2); a3 = f4add(a3, v3);
    }
    for (; i < n; i++) a0 = f4add(a0, xv[c[i] * 32 + lane]);
    float4 s = f4add(f4add(a0, a1), f4add(a2, a3));
    float rl = rliv[o];
    ((float4*)mean)[(long)o * 32 + lane] =
        make_float4(s.x * rl, s.y * rl, s.z * rl, s.w * rl);
}

// ---------------- conv GEMM + fused per-graph readout accumulation
__global__ __launch_bounds__(256) void k_conv(const float* __restrict__ xin, float* __restrict__ xout,
    const float* __restrict__ mean, const float* __restrict__ alive,
    const float* __restrict__ Wr, const float* __restrict__ Ws, const float* __restrict__ bias,
    float* __restrict__ hcat, int layer) {
    __shared__ __align__(16) float sm[16][HD];
    __shared__ __align__(16) float sx[16][HD];
    __shared__ float sal[16];
    __shared__ float red[2][HD];
    int t = threadIdx.x;
    long base = (long)blockIdx.x * 16;
    if (t < 16) sal[t] = alive[base + t];
    for (int idx = t; idx < 16 * HD; idx += 256) {
        int n = idx >> 7, f = idx & 127;
        long o = base + n;
        sm[n][f] = mean[o * HD + f];   // dead rows: stale but finite; excluded at write
        sx[n][f] = xin[o * HD + f];
    }
    __syncthreads();
    int j = t & 127, grp = t >> 7;
    float b = bias[j];
    float acc[8];
#pragma unroll
    for (int ni = 0; ni < 8; ni++) acc[ni] = b;

    const float4* smv = (const float4*)&sm[grp * 8][0];
    for (int k4 = 0; k4 < 32; k4++) {
        float w0 = Wr[(k4 * 4 + 0) * HD + j];
        float w1 = Wr[(k4 * 4 + 1) * HD + j];
        float w2 = Wr[(k4 * 4 + 2) * HD + j];
        float w3 = Wr[(k4 * 4 + 3) * HD + j];
#pragma unroll
        for (int ni = 0; ni < 8; ni++) {
            float4 m = smv[ni * 32 + k4];
            acc[ni] += m.x * w0 + m.y * w1 + m.z * w2 + m.w * w3;
        }
    }
    const float4* sxv = (const float4*)&sx[grp * 8][0];
    for (int k4 = 0; k4 < 32; k4++) {
        float w0 = Ws[(k4 * 4 + 0) * HD + j];
        float w1 = Ws[(k4 * 4 + 1) * HD + j];
        float w2 = Ws[(k4 * 4 + 2) * HD + j];
        float w3 = Ws[(k4 * 4 + 3) * HD + j];
#pragma unroll
        for (int ni = 0; ni < 8; ni++) {
            float4 m = sxv[ni * 32 + k4];
            acc[ni] += m.x * w0 + m.y * w1 + m.z * w2 + m.w * w3;
        }
    }
    float psum = 0.0f;
#pragma unroll
    for (int ni = 0; ni < 8; ni++) {
        long o = base + grp * 8 + ni;
        float v = fmaxf(acc[ni], 0.0f);
        if (sal[grp * 8 + ni] != 0.0f) {
            xout[o * HD + j] = v;
            psum += v;
        }
    }
    red[grp][j] = psum;
    __syncthreads();
    if (t < HD) {
        int g = (int)(base / NPG0);   // 25 blocks per graph, no block spans graphs
        atomicAdd(&hcat[g * (5 * HD) + layer * HD + t], red[0][t] + red[1][t]);
    }
}

// ---------------- pool scores, algebraically reduced:
// score[o] = mean_j(x_j . wr) + x_o . ws + b   (since mean and @wr commute for H->1)
// k_dots: per node, tr = x.wr ; tsb = x.ws + b
__global__ __launch_bounds__(256) void k_dots(const float* __restrict__ x,
    const float* __restrict__ wr, const float* __restrict__ ws, const float* __restrict__ pb,
    float* __restrict__ tr, float* __restrict__ tsb) {
    int lane = threadIdx.x;                    // 0..31
    int o = blockIdx.x * 8 + threadIdx.y;
    float4 xv = ((const float4*)x)[o * 32 + lane];
    float4 w1 = ((const float4*)wr)[lane];
    float4 w2 = ((const float4*)ws)[lane];
    float a = xv.x * w1.x + xv.y * w1.y + xv.z * w1.z + xv.w * w1.w;
    float c = xv.x * w2.x + xv.y * w2.y + xv.z * w2.z + xv.w * w2.w;
#pragma unroll
    for (int m = 1; m < 32; m <<= 1) {
        a += __shfl_xor(a, m);
        c += __shfl_xor(c, m);
    }
    if (lane == 0) { tr[o] = a; tsb[o] = c + pb[0]; }
}

__global__ __launch_bounds__(256) void k_score2(const int* __restrict__ cnt, const int* __restrict__ col,
    const float* __restrict__ alive, const float* __restrict__ rliv,
    const float* __restrict__ tr, const float* __restrict__ tsb,
    float* __restrict__ score) {
    int o = blockIdx.x * 256 + threadIdx.x;
    if (o >= NN) return;
    if (alive[o] == 0.0f) { score[o] = -INFINITY; return; }
    int n = cnt[o]; if (n > CAP) n = CAP;
    const int* c = &col[(long)o * CAP];
    float s = 0.0f;
    for (int i = 0; i < n; i++) s += tr[c[i]];   // dead x rows are zero -> tr==0
    score[o] = s * rliv[o] + tsb[o];
}

// ---------------- per-graph top-K (ties: lowest index), scale kept x by tanh(score), zero dropped
__global__ __launch_bounds__(256) void k_topk(float* __restrict__ x, float* __restrict__ alive,
                        const float* __restrict__ score, int K) {
    __shared__ float s[512];
    __shared__ float sc[NPG0];
    __shared__ float mult[NPG0];
    __shared__ unsigned char keep[NPG0];
    __shared__ int cnt_gt;
    int g = blockIdx.x, t = threadIdx.x;
    long nb = (long)g * NPG0;
    for (int i = t; i < 512; i += 256) {
        float v = (i < NPG0) ? score[nb + i] : -INFINITY;
        s[i] = v;
        if (i < NPG0) sc[i] = v;
    }
    if (t == 0) cnt_gt = 0;
    __syncthreads();
    for (int ksz = 2; ksz <= 512; ksz <<= 1) {
        for (int jsz = ksz >> 1; jsz >= 1; jsz >>= 1) {
            for (int i = t; i < 512; i += 256) {
                int ixj = i ^ jsz;
                if (ixj > i) {
                    float a = s[i], c = s[ixj];
                    bool up = ((i & ksz) == 0);
                    if ((a > c) == up) { s[i] = c; s[ixj] = a; }
                }
            }
            __syncthreads();
        }
    }
    float thr = s[512 - K];
    for (int n = t; n < NPG0; n += 256)
        if (sc[n] > thr) atomicAdd(&cnt_gt, 1);
    __syncthreads();
    if (t == 0) {
        int m = K - cnt_gt, tk = 0;
        for (int n = 0; n < NPG0; n++) {
            bool kp = sc[n] > thr;
            if (!kp && sc[n] == thr && tk < m) { kp = true; tk++; }
            keep[n] = kp ? 1 : 0;
        }
    }
    __syncthreads();
    for (int n = t; n < NPG0; n += 256) {
        mult[n] = keep[n] ? tanhf(sc[n]) : 0.0f;
        alive[nb + n] = keep[n] ? 1.0f : 0.0f;
    }
    __syncthreads();
    for (int idx = t; idx < NPG0 * HD; idx += 256) {
        int n = idx >> 7, f = idx & 127;
        x[(nb + n) * HD + f] *= mult[n];
    }
}

// ---------------- final MLP + log_softmax (hcat holds SUMS; divide by npg here)
__global__ __launch_bounds__(128) void k_mlp(const float* __restrict__ h, const float* __restrict__ w1,
    const float* __restrict__ b1, const float* __restrict__ w2,
    const float* __restrict__ b2, float* __restrict__ out) {
    __shared__ float h1[HD];
    __shared__ float red[HD];
    __shared__ float lg[2];
    const float inv[5] = {1.0f/400.0f, 1.0f/400.0f, 1.0f/320.0f, 1.0f/320.0f, 1.0f/256.0f};
    int g = blockIdx.x, j = threadIdx.x;
    const float* hg = &h[g * (5 * HD)];
    float acc = b1[j];
    for (int k = 0; k < 5 * HD; k++) acc += hg[k] * inv[k >> 7] * w1[k * HD + j];
    h1[j] = fmaxf(acc, 0.0f);
    __syncthreads();
    for (int c = 0; c < 2; c++) {
        red[j] = h1[j] * w2[j * 2 + c];
        __syncthreads();
        for (int st = 64; st > 0; st >>= 1) {
            if (j < st) red[j] += red[j + st];
            __syncthreads();
        }
        if (j == 0) lg[c] = red[0] + b2[c];
        __syncthreads();
    }
    if (j == 0) {
        float l0 = lg[0], l1 = lg[1];
        float m = fmaxf(l0, l1);
        float lse = m + logf(expf(l0 - m) + expf(l1 - m));
        out[g * 2 + 0] = l0 - lse;
        out[g * 2 + 1] = l1 - lse;
    }
}

extern "C" void kernel_launch(void* const* d_in, const int* in_sizes, int n_in,
                              void* d_out, int out_size, void* d_ws, size_t ws_size,
                              hipStream_t stream) {
    const float* x_in   = (const float*)d_in[0];
    const int*   eidx   = (const int*)d_in[1];
    const int*   e_src  = eidx;
    const int*   e_dst  = eidx + NE;
    const float* c1_wr  = (const float*)d_in[3];
    const float* c1_ws  = (const float*)d_in[4];
    const float* c1_b   = (const float*)d_in[5];
    const float* cs_wr  = (const float*)d_in[6];
    const float* cs_ws  = (const float*)d_in[7];
    const float* cs_b   = (const float*)d_in[8];
    const float* p_wr   = (const float*)d_in[9];
    const float* p_ws   = (const float*)d_in[10];
    const float* p_b    = (const float*)d_in[11];
    const float* l1_w   = (const float*)d_in[12];
    const float* l1_b   = (const float*)d_in[13];
    const float* l2_w   = (const float*)d_in[14];
    const float* l2_b   = (const float*)d_in[15];
    float* out = (float*)d_out;

    char* ws = (char*)d_ws;
    size_t off = 0;
    int*   cnt   = (int*)(ws + off);   off += (size_t)NN * 4;
    int*   col   = (int*)(ws + off);   off += (size_t)NN * CAP * 4;
    float* alive = (float*)(ws + off); off += (size_t)NN * 4;
    float* rliv  = (float*)(ws + off); off += (size_t)NN * 4;
    float* xbuf  = (float*)(ws + off); off += (size_t)NN * HD * 4;
    float* meanb = (float*)(ws + off); off += (size_t)NN * HD * 4;
    float* score = (float*)(ws + off); off += (size_t)NN * 4;
    float* trb   = (float*)(ws + off); off += (size_t)NN * 4;
    float* tsb   = (float*)(ws + off); off += (size_t)NN * 4;
    float* hcat  = (float*)(ws + off); off += (size_t)BGR * 5 * HD * 4;

    hipMemsetAsync(cnt, 0, (size_t)NN * 4, stream);
    hipMemsetAsync(hcat, 0, (size_t)BGR * 5 * HD * 4, stream);
    k_build<<<(NE + 255) / 256, 256, 0, stream>>>(e_src, e_dst, cnt, col);
    k_init_alive<<<(NN + 255) / 256, 256, 0, stream>>>(alive);
    k_rliv<<<NN / 256, 256, 0, stream>>>(cnt, col, alive, rliv);

    dim3 a32(32, 8);

    // conv1
    k_agg<<<NN / 8, a32, 0, stream>>>(x_in, cnt, col, alive, rliv, meanb);
    k_conv<<<NN / 16, 256, 0, stream>>>(x_in, xbuf, meanb, alive, c1_wr, c1_ws, c1_b, hcat, 0);

    // convs[0]
    k_agg<<<NN / 8, a32, 0, stream>>>(xbuf, cnt, col, alive, rliv, meanb);
    k_conv<<<NN / 16, 256, 0, stream>>>(xbuf, xbuf, meanb, alive, cs_wr + 0 * HD * HD, cs_ws + 0 * HD * HD, cs_b + 0 * HD, hcat, 1);

    // pool 0 (K=320)
    k_dots<<<NN / 8, a32, 0, stream>>>(xbuf, p_wr + 0 * HD, p_ws + 0 * HD, p_b + 0, trb, tsb);
    k_score2<<<NN / 256, 256, 0, stream>>>(cnt, col, alive, rliv, trb, tsb, score);
    k_topk<<<BGR, 256, 0, stream>>>(xbuf, alive, score, 320);
    k_rliv<<<NN / 256, 256, 0, stream>>>(cnt, col, alive, rliv);

    // convs[1]
    k_agg<<<NN / 8, a32, 0, stream>>>(xbuf, cnt, col, alive, rliv, meanb);
    k_conv<<<NN / 16, 256, 0, stream>>>(xbuf, xbuf, meanb, alive, cs_wr + 1 * HD * HD, cs_ws + 1 * HD * HD, cs_b + 1 * HD, hcat, 2);

    // convs[2]
    k_agg<<<NN / 8, a32, 0, stream>>>(xbuf, cnt, col, alive, rliv, meanb);
    k_conv<<<NN / 16, 256, 0, stream>>>(xbuf, xbuf, meanb, alive, cs_wr + 2 * HD * HD, cs_ws + 2 * HD * HD, cs_b + 2 * HD, hcat, 3);

    // pool 1 (K=256)
    k_dots<<<NN / 8, a32, 0, stream>>>(xbuf, p_wr + 1 * HD, p_ws + 1 * HD, p_b + 1, trb, tsb);
    k_score2<<<NN / 256, 256, 0, stream>>>(cnt, col, alive, rliv, trb, tsb, score);
    k_topk<<<BGR, 256, 0, stream>>>(xbuf, alive, score, 256);
    k_rliv<<<NN / 256, 256, 0, stream>>>(cnt, col, alive, rliv);

    // convs[3]
    k_agg<<<NN / 8, a32, 0, stream>>>(xbuf, cnt, col, alive, rliv, meanb);
    k_conv<<<NN / 16, 256, 0, stream>>>(xbuf, xbuf, meanb, alive, cs_wr + 3 * HD * HD, cs_ws + 3 * HD * HD, cs_b + 3 * HD, hcat, 4);

    // MLP head
    k_mlp<<<BGR, HD, 0, stream>>>(hcat, l1_w, l1_b, l2_w, l2_b, out);
}

// Round 3
// 753.718 us; speedup vs baseline: 3.7993x; 1.8397x over previous
//
#include <hip/hip_runtime.h>
#include <math.h>

#define BGR 256        // graphs
#define NPG0 400       // nodes per graph (initial)
#define NN (BGR*NPG0)  // 102400 nodes
#define NE (NN*16)     // 1638400 edges
#define HD 128
#define CAP 64         // max in-degree capacity

typedef __attribute__((ext_vector_type(8))) short short8;
typedef __attribute__((ext_vector_type(4))) float floatx4;

__device__ __forceinline__ float4 f4add(float4 a, float4 b) {
    return make_float4(a.x + b.x, a.y + b.y, a.z + b.z, a.w + b.w);
}
__device__ __forceinline__ unsigned short f2b(float f) {
    unsigned int u = __builtin_bit_cast(unsigned int, f);
    unsigned int r = (u + 0x7fffu + ((u >> 16) & 1u)) >> 16;
    return (unsigned short)r;
}
__device__ __forceinline__ float b2f(unsigned short h) {
    return __builtin_bit_cast(float, (unsigned int)h << 16);
}

// ---------------- CSR build (fixed capacity, by dst) ----------------
__global__ void k_build(const int* __restrict__ src, const int* __restrict__ dst,
                        int* __restrict__ cnt, int* __restrict__ col) {
    int e = blockIdx.x * 256 + threadIdx.x;
    if (e >= NE) return;
    int d = dst[e];
    int s = src[e];
    int i = atomicAdd(&cnt[d], 1);
    if (i < CAP) col[d * CAP + i] = s;
}

__global__ void k_init_alive(float* __restrict__ alive) {
    int i = blockIdx.x * 256 + threadIdx.x;
    if (i < NN) alive[i] = 1.0f;
}

// rliv[o] = 1 / max(sum_j alive[src_j], 1)
__global__ void k_rliv(const int* __restrict__ cnt, const int* __restrict__ col,
                       const float* __restrict__ alive, float* __restrict__ rliv) {
    int o = blockIdx.x * 256 + threadIdx.x;
    if (o >= NN) return;
    int n = cnt[o]; if (n > CAP) n = CAP;
    const int* c = &col[(long)o * CAP];
    float s = 0.0f;
    for (int i = 0; i < n; i++) s += alive[c[i]];
    rliv[o] = 1.0f / fmaxf(s, 1.0f);
}

// ---------------- W -> bf16, transposed: bt[m][n*128 + k] = bf16(W_m[k*128 + n])
__global__ void k_wcvt(const float* __restrict__ c1_wr, const float* __restrict__ c1_ws,
                       const float* __restrict__ cs_wr, const float* __restrict__ cs_ws,
                       unsigned short* __restrict__ bt) {
    int m = blockIdx.y;
    int idx = blockIdx.x * 256 + threadIdx.x;       // 0..16383
    const float* W = (m == 0) ? c1_wr : (m == 1) ? c1_ws
                   : (m < 6) ? (cs_wr + (m - 2) * HD * HD) : (cs_ws + (m - 6) * HD * HD);
    int n = idx >> 7, k = idx & 127;
    bt[m * HD * HD + idx] = f2b(W[k * HD + n]);
}

// ---------------- mean aggregation (bf16 out), float4/uint2 + 4-way unroll + XCD swizzle
template<bool XF32>
__global__ __launch_bounds__(256) void k_agg(const void* __restrict__ x_v,
                      const int* __restrict__ cnt, const int* __restrict__ col,
                      const float* __restrict__ alive, const float* __restrict__ rliv,
                      unsigned short* __restrict__ mean) {
    int b = blockIdx.x;
    int r = b & 7, q = b >> 3;
    int g = r + (q / 50) * 8;
    int o = g * NPG0 + (q % 50) * 8 + threadIdx.y;
    if (alive[o] == 0.0f) return;
    int lane = threadIdx.x;     // 0..31, 4 features each
    int n = cnt[o]; if (n > CAP) n = CAP;
    const int* c = &col[(long)o * CAP];
    float4 a0 = make_float4(0, 0, 0, 0), a1 = a0, a2 = a0, a3 = a0;
    if (XF32) {
        const float4* xv = (const float4*)x_v;
        int i = 0;
        for (; i + 4 <= n; i += 4) {
            int s0 = c[i], s1 = c[i + 1], s2 = c[i + 2], s3 = c[i + 3];
            a0 = f4add(a0, xv[s0 * 32 + lane]);
            a1 = f4add(a1, xv[s1 * 32 + lane]);
            a2 = f4add(a2, xv[s2 * 32 + lane]);
            a3 = f4add(a3, xv[s3 * 32 + lane]);
        }
        for (; i < n; i++) a0 = f4add(a0, xv[c[i] * 32 + lane]);
    } else {
        const uint2* xv = (const uint2*)x_v;
        int i = 0;
        for (; i + 4 <= n; i += 4) {
            uint2 u0 = xv[c[i] * 32 + lane];
            uint2 u1 = xv[c[i + 1] * 32 + lane];
            uint2 u2 = xv[c[i + 2] * 32 + lane];
            uint2 u3 = xv[c[i + 3] * 32 + lane];
            a0.x += b2f(u0.x & 0xffff); a0.y += b2f(u0.x >> 16);
            a0.z += b2f(u0.y & 0xffff); a0.w += b2f(u0.y >> 16);
            a1.x += b2f(u1.x & 0xffff); a1.y += b2f(u1.x >> 16);
            a1.z += b2f(u1.y & 0xffff); a1.w += b2f(u1.y >> 16);
            a2.x += b2f(u2.x & 0xffff); a2.y += b2f(u2.x >> 16);
            a2.z += b2f(u2.y & 0xffff); a2.w += b2f(u2.y >> 16);
            a3.x += b2f(u3.x & 0xffff); a3.y += b2f(u3.x >> 16);
            a3.z += b2f(u3.y & 0xffff); a3.w += b2f(u3.y >> 16);
        }
        for (; i < n; i++) {
            uint2 u0 = xv[c[i] * 32 + lane];
            a0.x += b2f(u0.x & 0xffff); a0.y += b2f(u0.x >> 16);
            a0.z += b2f(u0.y & 0xffff); a0.w += b2f(u0.y >> 16);
        }
    }
    float4 s = f4add(f4add(a0, a1), f4add(a2, a3));
    float rl = rliv[o];
    uint2 w;
    w.x = (unsigned int)f2b(s.x * rl) | ((unsigned int)f2b(s.y * rl) << 16);
    w.y = (unsigned int)f2b(s.z * rl) | ((unsigned int)f2b(s.w * rl) << 16);
    ((uint2*)mean)[(long)o * 32 + lane] = w;
}

// ---------------- MFMA conv: xout = relu(mean@Wr + x@Ws + b), 128 nodes x 128 cols / block
// + fused per-graph readout sum into hcat (atomics)
template<bool XF32>
__global__ __launch_bounds__(256) void k_conv_mfma(
    const void* __restrict__ xin_v, unsigned short* __restrict__ xout,
    const unsigned short* __restrict__ meanb, const float* __restrict__ alive,
    const unsigned short* __restrict__ wr_bt, const unsigned short* __restrict__ ws_bt,
    const float* __restrict__ bias, float* __restrict__ hcat, int layer)
{
    __shared__ unsigned short sA[128 * 136];   // +8 pad per row
    __shared__ float sAl[128];
    int t = threadIdx.x;
    int base = blockIdx.x * 128;
    int lane = t & 63, wid = t >> 6;
    int quad = lane >> 4, l15 = lane & 15;
    int wrow0 = (wid & 1) * 64, wcol0 = (wid >> 1) * 64;

    if (t < 128) sAl[t] = alive[base + t];

    // ---- stage 0: A = mean (bf16 global), B = Wr^T
    for (int it = 0; it < 16; ++it) {
        int flat = it * 256 + t;
        int row = flat >> 5, c4 = flat & 31;
        uint2 w = *(const uint2*)&meanb[(long)(base + row) * HD + c4 * 4];
        *(uint2*)&sA[row * 136 + c4 * 4] = w;
    }
    short8 Bf[4][4];
#pragma unroll
    for (int ct = 0; ct < 4; ++ct)
#pragma unroll
        for (int ks = 0; ks < 4; ++ks)
            Bf[ct][ks] = *(const short8*)&wr_bt[(wcol0 + ct * 16 + l15) * HD + ks * 32 + quad * 8];
    floatx4 acc[4][4];
#pragma unroll
    for (int ct = 0; ct < 4; ++ct) {
        float b = bias[wcol0 + ct * 16 + l15];
#pragma unroll
        for (int nt = 0; nt < 4; ++nt) { acc[nt][ct][0] = b; acc[nt][ct][1] = b; acc[nt][ct][2] = b; acc[nt][ct][3] = b; }
    }
    __syncthreads();
#pragma unroll
    for (int ks = 0; ks < 4; ++ks) {
        short8 Af[4];
#pragma unroll
        for (int nt = 0; nt < 4; ++nt)
            Af[nt] = *(const short8*)&sA[(wrow0 + nt * 16 + l15) * 136 + ks * 32 + quad * 8];
#pragma unroll
        for (int ct = 0; ct < 4; ++ct)
#pragma unroll
            for (int nt = 0; nt < 4; ++nt)
                acc[nt][ct] = __builtin_amdgcn_mfma_f32_16x16x32_bf16(Af[nt], Bf[ct][ks], acc[nt][ct], 0, 0, 0);
    }
    __syncthreads();
    // ---- stage 1: A = x, B = Ws^T
    for (int it = 0; it < 16; ++it) {
        int flat = it * 256 + t;
        int row = flat >> 5, c4 = flat & 31;
        uint2 w;
        if (XF32) {
            float4 v = ((const float4*)xin_v)[(long)(base + row) * 32 + c4];
            w.x = (unsigned int)f2b(v.x) | ((unsigned int)f2b(v.y) << 16);
            w.y = (unsigned int)f2b(v.z) | ((unsigned int)f2b(v.w) << 16);
        } else {
            w = ((const uint2*)xin_v)[(long)(base + row) * 32 + c4];
        }
        *(uint2*)&sA[row * 136 + c4 * 4] = w;
    }
#pragma unroll
    for (int ct = 0; ct < 4; ++ct)
#pragma unroll
        for (int ks = 0; ks < 4; ++ks)
            Bf[ct][ks] = *(const short8*)&ws_bt[(wcol0 + ct * 16 + l15) * HD + ks * 32 + quad * 8];
    __syncthreads();
#pragma unroll
    for (int ks = 0; ks < 4; ++ks) {
        short8 Af[4];
#pragma unroll
        for (int nt = 0; nt < 4; ++nt)
            Af[nt] = *(const short8*)&sA[(wrow0 + nt * 16 + l15) * 136 + ks * 32 + quad * 8];
#pragma unroll
        for (int ct = 0; ct < 4; ++ct)
#pragma unroll
            for (int nt = 0; nt < 4; ++nt)
                acc[nt][ct] = __builtin_amdgcn_mfma_f32_16x16x32_bf16(Af[nt], Bf[ct][ks], acc[nt][ct], 0, 0, 0);
    }
    // ---- epilogue: relu, alive-gate, bf16 store, per-graph readout
    int g0 = base / NPG0;
    int cut = (g0 + 1) * NPG0 - base;     // rows >= cut belong to g0+1
    bool hasB = cut < 128;
#pragma unroll
    for (int ct = 0; ct < 4; ++ct) {
        int j = wcol0 + ct * 16 + l15;
        float ps0 = 0.0f, ps1 = 0.0f;
#pragma unroll
        for (int nt = 0; nt < 4; ++nt) {
#pragma unroll
            for (int rr = 0; rr < 4; ++rr) {
                int row = wrow0 + nt * 16 + quad * 4 + rr;
                float v = fmaxf(acc[nt][ct][rr], 0.0f);
                if (sAl[row] != 0.0f) {
                    xout[(long)(base + row) * HD + j] = f2b(v);
                    if (row < cut) ps0 += v; else ps1 += v;
                }
            }
        }
        ps0 += __shfl_xor(ps0, 16); ps0 += __shfl_xor(ps0, 32);
        if (hasB) { ps1 += __shfl_xor(ps1, 16); ps1 += __shfl_xor(ps1, 32); }
        if (quad == 0) {
            atomicAdd(&hcat[g0 * (5 * HD) + layer * HD + j], ps0);
            if (hasB) atomicAdd(&hcat[(g0 + 1) * (5 * HD) + layer * HD + j], ps1);
        }
    }
}

// ---------------- pool scores (x is bf16): tr = x.wr ; tsb = x.ws + b
__global__ __launch_bounds__(256) void k_dots(const unsigned short* __restrict__ x,
    const float* __restrict__ wr, const float* __restrict__ ws, const float* __restrict__ pb,
    float* __restrict__ tr, float* __restrict__ tsb) {
    int lane = threadIdx.x;                    // 0..31
    int o = blockIdx.x * 8 + threadIdx.y;
    uint2 u = ((const uint2*)x)[(long)o * 32 + lane];
    float x0 = b2f(u.x & 0xffff), x1 = b2f(u.x >> 16), x2 = b2f(u.y & 0xffff), x3 = b2f(u.y >> 16);
    float4 w1 = ((const float4*)wr)[lane];
    float4 w2 = ((const float4*)ws)[lane];
    float a = x0 * w1.x + x1 * w1.y + x2 * w1.z + x3 * w1.w;
    float c = x0 * w2.x + x1 * w2.y + x2 * w2.z + x3 * w2.w;
#pragma unroll
    for (int m = 1; m < 32; m <<= 1) {
        a += __shfl_xor(a, m);
        c += __shfl_xor(c, m);
    }
    if (lane == 0) { tr[o] = a; tsb[o] = c + pb[0]; }
}

__global__ __launch_bounds__(256) void k_score2(const int* __restrict__ cnt, const int* __restrict__ col,
    const float* __restrict__ alive, const float* __restrict__ rliv,
    const float* __restrict__ tr, const float* __restrict__ tsb,
    float* __restrict__ score) {
    int o = blockIdx.x * 256 + threadIdx.x;
    if (o >= NN) return;
    if (alive[o] == 0.0f) { score[o] = -INFINITY; return; }
    int n = cnt[o]; if (n > CAP) n = CAP;
    const int* c = &col[(long)o * CAP];
    float s = 0.0f;
    for (int i = 0; i < n; i++) s += tr[c[i]];
    score[o] = s * rliv[o] + tsb[o];
}

// ---------------- per-graph top-K (ties: lowest index), scale kept x by tanh(score), zero dropped
__global__ __launch_bounds__(256) void k_topk(unsigned short* __restrict__ x, float* __restrict__ alive,
                        const float* __restrict__ score, int K) {
    __shared__ float s[512];
    __shared__ float sc[NPG0];
    __shared__ float mult[NPG0];
    __shared__ unsigned char keep[NPG0];
    __shared__ int cnt_gt;
    int g = blockIdx.x, t = threadIdx.x;
    long nb = (long)g * NPG0;
    for (int i = t; i < 512; i += 256) {
        float v = (i < NPG0) ? score[nb + i] : -INFINITY;
        s[i] = v;
        if (i < NPG0) sc[i] = v;
    }
    if (t == 0) cnt_gt = 0;
    __syncthreads();
    for (int ksz = 2; ksz <= 512; ksz <<= 1) {
        for (int jsz = ksz >> 1; jsz >= 1; jsz >>= 1) {
            for (int i = t; i < 512; i += 256) {
                int ixj = i ^ jsz;
                if (ixj > i) {
                    float a = s[i], c = s[ixj];
                    bool up = ((i & ksz) == 0);
                    if ((a > c) == up) { s[i] = c; s[ixj] = a; }
                }
            }
            __syncthreads();
        }
    }
    float thr = s[512 - K];
    for (int n = t; n < NPG0; n += 256)
        if (sc[n] > thr) atomicAdd(&cnt_gt, 1);
    __syncthreads();
    if (t == 0) {
        int m = K - cnt_gt, tk = 0;
        for (int n = 0; n < NPG0; n++) {
            bool kp = sc[n] > thr;
            if (!kp && sc[n] == thr && tk < m) { kp = true; tk++; }
            keep[n] = kp ? 1 : 0;
        }
    }
    __syncthreads();
    for (int n = t; n < NPG0; n += 256) {
        mult[n] = keep[n] ? tanhf(sc[n]) : 0.0f;
        alive[nb + n] = keep[n] ? 1.0f : 0.0f;
    }
    __syncthreads();
    // x *= mult (bf16, 4 at a time)
    for (int idx = t; idx < NPG0 * HD / 4; idx += 256) {
        int n = idx >> 5, c4 = idx & 31;
        uint2* p = (uint2*)&x[(nb + n) * HD + c4 * 4];
        uint2 u = *p;
        float m = mult[n];
        uint2 w;
        w.x = (unsigned int)f2b(b2f(u.x & 0xffff) * m) | ((unsigned int)f2b(b2f(u.x >> 16) * m) << 16);
        w.y = (unsigned int)f2b(b2f(u.y & 0xffff) * m) | ((unsigned int)f2b(b2f(u.y >> 16) * m) << 16);
        *p = w;
    }
}

// ---------------- final MLP + log_softmax (hcat holds SUMS; divide by npg here)
__global__ __launch_bounds__(128) void k_mlp(const float* __restrict__ h, const float* __restrict__ w1,
    const float* __restrict__ b1, const float* __restrict__ w2,
    const float* __restrict__ b2, float* __restrict__ out) {
    __shared__ float h1[HD];
    __shared__ float red[HD];
    __shared__ float lg[2];
    const float inv[5] = {1.0f/400.0f, 1.0f/400.0f, 1.0f/320.0f, 1.0f/320.0f, 1.0f/256.0f};
    int g = blockIdx.x, j = threadIdx.x;
    const float* hg = &h[g * (5 * HD)];
    float acc = b1[j];
    for (int k = 0; k < 5 * HD; k++) acc += hg[k] * inv[k >> 7] * w1[k * HD + j];
    h1[j] = fmaxf(acc, 0.0f);
    __syncthreads();
    for (int c = 0; c < 2; c++) {
        red[j] = h1[j] * w2[j * 2 + c];
        __syncthreads();
        for (int st = 64; st > 0; st >>= 1) {
            if (j < st) red[j] += red[j + st];
            __syncthreads();
        }
        if (j == 0) lg[c] = red[0] + b2[c];
        __syncthreads();
    }
    if (j == 0) {
        float l0 = lg[0], l1 = lg[1];
        float m = fmaxf(l0, l1);
        float lse = m + logf(expf(l0 - m) + expf(l1 - m));
        out[g * 2 + 0] = l0 - lse;
        out[g * 2 + 1] = l1 - lse;
    }
}

extern "C" void kernel_launch(void* const* d_in, const int* in_sizes, int n_in,
                              void* d_out, int out_size, void* d_ws, size_t ws_size,
                              hipStream_t stream) {
    const float* x_in   = (const float*)d_in[0];
    const int*   eidx   = (const int*)d_in[1];
    const int*   e_src  = eidx;
    const int*   e_dst  = eidx + NE;
    const float* c1_wr  = (const float*)d_in[3];
    const float* c1_ws  = (const float*)d_in[4];
    const float* c1_b   = (const float*)d_in[5];
    const float* cs_wr  = (const float*)d_in[6];
    const float* cs_ws  = (const float*)d_in[7];
    const float* cs_b   = (const float*)d_in[8];
    const float* p_wr   = (const float*)d_in[9];
    const float* p_ws   = (const float*)d_in[10];
    const float* p_b    = (const float*)d_in[11];
    const float* l1_w   = (const float*)d_in[12];
    const float* l1_b   = (const float*)d_in[13];
    const float* l2_w   = (const float*)d_in[14];
    const float* l2_b   = (const float*)d_in[15];
    float* out = (float*)d_out;

    char* ws = (char*)d_ws;
    size_t off = 0;
    int*   cnt   = (int*)(ws + off);             off += (size_t)NN * 4;
    int*   col   = (int*)(ws + off);             off += (size_t)NN * CAP * 4;
    float* alive = (float*)(ws + off);           off += (size_t)NN * 4;
    float* rliv  = (float*)(ws + off);           off += (size_t)NN * 4;
    unsigned short* xbuf  = (unsigned short*)(ws + off); off += (size_t)NN * HD * 2;
    unsigned short* meanb = (unsigned short*)(ws + off); off += (size_t)NN * HD * 2;
    float* score = (float*)(ws + off);           off += (size_t)NN * 4;
    float* trb   = (float*)(ws + off);           off += (size_t)NN * 4;
    float* tsb   = (float*)(ws + off);           off += (size_t)NN * 4;
    float* hcat  = (float*)(ws + off);           off += (size_t)BGR * 5 * HD * 4;
    unsigned short* wbt = (unsigned short*)(ws + off); off += (size_t)10 * HD * HD * 2;

    hipMemsetAsync(cnt, 0, (size_t)NN * 4, stream);
    hipMemsetAsync(hcat, 0, (size_t)BGR * 5 * HD * 4, stream);
    k_build<<<(NE + 255) / 256, 256, 0, stream>>>(e_src, e_dst, cnt, col);
    k_init_alive<<<(NN + 255) / 256, 256, 0, stream>>>(alive);
    k_rliv<<<NN / 256, 256, 0, stream>>>(cnt, col, alive, rliv);
    k_wcvt<<<dim3(64, 10), 256, 0, stream>>>(c1_wr, c1_ws, cs_wr, cs_ws, wbt);

    dim3 a32(32, 8);
    unsigned short* bt_wr[5] = { wbt + 0 * HD * HD, wbt + 2 * HD * HD, wbt + 3 * HD * HD, wbt + 4 * HD * HD, wbt + 5 * HD * HD };
    unsigned short* bt_ws[5] = { wbt + 1 * HD * HD, wbt + 6 * HD * HD, wbt + 7 * HD * HD, wbt + 8 * HD * HD, wbt + 9 * HD * HD };

    // conv1 (x fp32 in)
    k_agg<true><<<NN / 8, a32, 0, stream>>>(x_in, cnt, col, alive, rliv, meanb);
    k_conv_mfma<true><<<NN / 128, 256, 0, stream>>>(x_in, xbuf, meanb, alive, bt_wr[0], bt_ws[0], c1_b, hcat, 0);

    // convs[0]
    k_agg<false><<<NN / 8, a32, 0, stream>>>(xbuf, cnt, col, alive, rliv, meanb);
    k_conv_mfma<false><<<NN / 128, 256, 0, stream>>>(xbuf, xbuf, meanb, alive, bt_wr[1], bt_ws[1], cs_b + 0 * HD, hcat, 1);

    // pool 0 (K=320)
    k_dots<<<NN / 8, a32, 0, stream>>>(xbuf, p_wr + 0 * HD, p_ws + 0 * HD, p_b + 0, trb, tsb);
    k_score2<<<NN / 256, 256, 0, stream>>>(cnt, col, alive, rliv, trb, tsb, score);
    k_topk<<<BGR, 256, 0, stream>>>(xbuf, alive, score, 320);
    k_rliv<<<NN / 256, 256, 0, stream>>>(cnt, col, alive, rliv);

    // convs[1]
    k_agg<false><<<NN / 8, a32, 0, stream>>>(xbuf, cnt, col, alive, rliv, meanb);
    k_conv_mfma<false><<<NN / 128, 256, 0, stream>>>(xbuf, xbuf, meanb, alive, bt_wr[2], bt_ws[2], cs_b + 1 * HD, hcat, 2);

    // convs[2]
    k_agg<false><<<NN / 8, a32, 0, stream>>>(xbuf, cnt, col, alive, rliv, meanb);
    k_conv_mfma<false><<<NN / 128, 256, 0, stream>>>(xbuf, xbuf, meanb, alive, bt_wr[3], bt_ws[3], cs_b + 2 * HD, hcat, 3);

    // pool 1 (K=256)
    k_dots<<<NN / 8, a32, 0, stream>>>(xbuf, p_wr + 1 * HD, p_ws + 1 * HD, p_b + 1, trb, tsb);
    k_score2<<<NN / 256, 256, 0, stream>>>(cnt, col, alive, rliv, trb, tsb, score);
    k_topk<<<BGR, 256, 0, stream>>>(xbuf, alive, score, 256);
    k_rliv<<<NN / 256, 256, 0, stream>>>(cnt, col, alive, rliv);

    // convs[3]
    k_agg<false><<<NN / 8, a32, 0, stream>>>(xbuf, cnt, col, alive, rliv, meanb);
    k_conv_mfma<false><<<NN / 128, 256, 0, stream>>>(xbuf, xbuf, meanb, alive, bt_wr[4], bt_ws[4], cs_b + 3 * HD, hcat, 4);

    // MLP head
    k_mlp<<<BGR, HD, 0, stream>>>(hcat, l1_w, l1_b, l2_w, l2_b, out);
}